// Round 4
// baseline (138.694 us; speedup 1.0000x reference)
//
#include <hip/hip_runtime.h>
#include <stdint.h>

#define NB 4
#define NC 17
#define HH 8
#define SS 512
#define DD 64
#define CT 32   // columns per block tile

typedef __attribute__((ext_vector_type(8))) short bf16x8;
typedef __attribute__((ext_vector_type(4))) float f32x4;

// ws layout (bytes):
//   W1mbf : [17][8][64][64] bf16 = 1,114,112
//   ridx  : [8][512] int (rows grouped by bucket)
//   gst   : [8][6] int group offsets
#define WS_W1   0
#define WS_RIDX 1114112
#define WS_GST  (WS_RIDX + 16384)

__device__ __forceinline__ unsigned short f2bf(float f) {
  unsigned int x; __builtin_memcpy(&x, &f, 4);
  return (unsigned short)((x + 0x7fff + ((x >> 16) & 1)) >> 16);
}
// load 8 consecutive floats, round to bf16, pack into MFMA A/B fragment
__device__ __forceinline__ bf16x8 cvt8(const float* p) {
  float4 a = *(const float4*)p;
  float4 b = *(const float4*)(p + 4);
  union { bf16x8 v; unsigned short u[8]; } t;
  t.u[0] = f2bf(a.x); t.u[1] = f2bf(a.y); t.u[2] = f2bf(a.z); t.u[3] = f2bf(a.w);
  t.u[4] = f2bf(b.x); t.u[5] = f2bf(b.y); t.u[6] = f2bf(b.z); t.u[7] = f2bf(b.w);
  return t.v;
}

// ---- K0: blocks 0..7: per-b counting sort of row positions by bucket bi.
//          blocks 8..143: W1mbf[c][h][.] = sum_B W1[B][h][.]*softmax(alpha)[c,B,h]
__global__ __launch_bounds__(256) void k_prep(const int* __restrict__ bseq,
                                              const float* __restrict__ W1,
                                              const float* __restrict__ alpha,
                                              int* __restrict__ ridx,
                                              int* __restrict__ gst,
                                              unsigned short* __restrict__ W1mbf) {
  int tid = threadIdx.x;
  if (blockIdx.x < 8) {
    int b = blockIdx.x;
    __shared__ int cnt[5], base[6], cur[5];
    if (tid < 5) cnt[tid] = 0;
    __syncthreads();
    for (int j = tid; j < SS; j += blockDim.x) atomicAdd(&cnt[bseq[b * SS + j]], 1);
    __syncthreads();
    if (tid == 0) {
      base[0] = 0;
      for (int k = 0; k < 5; k++) base[k + 1] = base[k] + cnt[k];
      for (int k = 0; k < 6; k++) gst[b * 6 + k] = base[k];
    }
    __syncthreads();
    if (tid < 5) cur[tid] = base[tid];
    __syncthreads();
    for (int j = tid; j < SS; j += blockDim.x) {
      int p = atomicAdd(&cur[bseq[b * SS + j]], 1);
      ridx[b * SS + p] = j;
    }
  } else {
    int cb = blockIdx.x - 8;
    int c = cb >> 3, hh = cb & 7;
    __shared__ float sm[NB];
    if (tid == 0) {
      float a[NB], mx = -1e30f;
      for (int B = 0; B < NB; B++) { a[B] = alpha[(c * NB + B) * HH + hh]; mx = fmaxf(mx, a[B]); }
      float s = 0.f;
      for (int B = 0; B < NB; B++) { a[B] = __expf(a[B] - mx); s += a[B]; }
      for (int B = 0; B < NB; B++) sm[B] = a[B] / s;
    }
    __syncthreads();
    float s0 = sm[0], s1 = sm[1], s2 = sm[2], s3 = sm[3];
    for (int idx = tid; idx < DD * DD; idx += blockDim.x) {
      float v = W1[((0 * HH + hh) * DD * DD) + idx] * s0 +
                W1[((1 * HH + hh) * DD * DD) + idx] * s1 +
                W1[((2 * HH + hh) * DD * DD) + idx] * s2 +
                W1[((3 * HH + hh) * DD * DD) + idx] * s3;
      W1mbf[((size_t)(c * HH + hh)) * DD * DD + idx] = f2bf(v);
    }
  }
}

// ---- Fused: per (bh, 32-col tile): build T[5][32][64] in LDS, then scores GEMM.
// Block swizzle: bh = bx & 63 so all col-tiles of one bh share an XCD (L2 reuse
// of q[bh], key[bh], W1mbf[h]).
__global__ __launch_bounds__(256) void k_fused(const float* __restrict__ query,
                                               const float* __restrict__ key,
                                               const int* __restrict__ bseq,
                                               const unsigned short* __restrict__ W1mbf,
                                               const int* __restrict__ ridx,
                                               const int* __restrict__ gst,
                                               float* __restrict__ out) {
  int bx = blockIdx.x;
  int bh = bx & 63, jt = bx >> 6;
  int b = bh >> 3, h = bh & 7;
  int j0 = jt * CT;
  int tid = threadIdx.x, wave = tid >> 6, lane = tid & 63;
  int quad = lane >> 4, l16 = lane & 15;

  __shared__ __align__(16) unsigned short Tl[5][CT][72];  // 23,040 B
  __shared__ int ord[CT], lgs[6], cnt[5], cur[5];
  __shared__ int p1list[40], p2list[40];
  __shared__ int n1s[5], n2s[5], n1b[5], n2b[5];
  __shared__ int n1tot, n2tot;

  // ---- local column grouping by bj + tile-list build ----
  if (tid < 5) cnt[tid] = 0;
  __syncthreads();
  int mybj = 0;
  if (tid < CT) { mybj = bseq[b * SS + j0 + tid]; atomicAdd(&cnt[mybj], 1); }
  __syncthreads();
  if (tid == 0) {
    lgs[0] = 0;
    for (int a = 0; a < 5; a++) lgs[a + 1] = lgs[a] + cnt[a];
  }
  __syncthreads();
  if (tid < 5) cur[tid] = lgs[tid];
  __syncthreads();
  if (tid < CT) ord[atomicAdd(&cur[mybj], 1)] = tid;
  if (tid < 5) {
    int a = tid;
    int tiles = (lgs[a + 1] - lgs[a] + 15) >> 4;
    n1s[a] = tiles * ((a == 0) ? 1 : 5);
    int gs = gst[b * 6 + a], ge = gst[b * 6 + a + 1];
    n2s[a] = (ge - gs + 15) >> 4;
  }
  __syncthreads();
  if (tid == 0) {
    int a0 = 0, a1 = 0;
    for (int a = 0; a < 5; a++) {
      n1b[a] = a0; a0 += n1s[a];
      n2b[a] = a1; a1 += n2s[a];
    }
    n1tot = a0; n2tot = a1;
  }
  __syncthreads();
  if (tid < 5) {
    int a = tid;
    int ls = lgs[a], le = lgs[a + 1];
    int w = n1b[a];
    for (int t0 = ls; t0 < le; t0 += 16) {
      if (a == 0) {
        p1list[w++] = t0 | (le << 5) | (1 << 19);  // c=0, bcast to all planes
      } else {
        for (int B = 0; B < 5; B++) {
          int c = (B == 0) ? 0 : (B - 1) * NB + a;
          p1list[w++] = t0 | (le << 5) | (c << 11) | (B << 16);
        }
      }
    }
    int gs = gst[b * 6 + a], ge = gst[b * 6 + a + 1];
    w = n2b[a];
    for (int p0 = gs; p0 < ge; p0 += 16)
      p2list[w++] = p0 | (ge << 10) | (a << 20);
  }
  __syncthreads();

  // ---- phase 1: T[B][col][m] = sum_n key[col][n] * W_c(B,bj)[m][n] ----
  for (int idx = wave; idx < n1tot; idx += 4) {
    int e = p1list[idx];
    int t0 = e & 31, le = (e >> 5) & 63, c = (e >> 11) & 31, B = (e >> 16) & 7;
    int bc = (e >> 19) & 1;
    const unsigned short* Wc = W1mbf + ((size_t)(c * HH + h) << 12);
    int p = t0 + l16; if (p > le - 1) p = le - 1;
    int cl = ord[p];
    const float* kp = &key[((size_t)(bh * SS + j0 + cl)) * DD + quad * 8];
    bf16x8 af0 = cvt8(kp);
    bf16x8 af1 = cvt8(kp + 32);
    int cr[4];
#pragma unroll
    for (int reg = 0; reg < 4; reg++) {
      int pr = t0 + quad * 4 + reg;
      cr[reg] = (pr < le) ? ord[pr] : -1;
    }
#pragma unroll
    for (int nt = 0; nt < 4; nt++) {
      const unsigned short* wp = &Wc[(nt * 16 + l16) * DD + quad * 8];
      bf16x8 b0 = *(const bf16x8*)wp;
      bf16x8 b1 = *(const bf16x8*)(wp + 32);
      f32x4 acc = {0.f, 0.f, 0.f, 0.f};
      acc = __builtin_amdgcn_mfma_f32_16x16x32_bf16(af0, b0, acc, 0, 0, 0);
      acc = __builtin_amdgcn_mfma_f32_16x16x32_bf16(af1, b1, acc, 0, 0, 0);
#pragma unroll
      for (int reg = 0; reg < 4; reg++) {
        if (cr[reg] >= 0) {
          unsigned short v = f2bf(acc[reg]);
          if (bc) {
#pragma unroll
            for (int Bw = 0; Bw < 5; Bw++) Tl[Bw][cr[reg]][nt * 16 + l16] = v;
          } else {
            Tl[B][cr[reg]][nt * 16 + l16] = v;
          }
        }
      }
    }
  }
  __syncthreads();

  // ---- phase 2: out[i][j0+jj] = q[i,:] dot Tl[bi(i)][jj][:] ----
  for (int idx = wave; idx < n2tot; idx += 4) {
    int e = p2list[idx];
    int p0 = e & 1023, ge = (e >> 10) & 1023, B = e >> 20;
    int p = p0 + l16; if (p > ge - 1) p = ge - 1;
    int r = ridx[b * SS + p];
    const float* qp = &query[((size_t)(bh * SS + r)) * DD + quad * 8];
    bf16x8 af0 = cvt8(qp);
    bf16x8 af1 = cvt8(qp + 32);
    int rr[4];
#pragma unroll
    for (int reg = 0; reg < 4; reg++) {
      int pr = p0 + quad * 4 + reg;
      rr[reg] = (pr < ge) ? ridx[b * SS + pr] : -1;
    }
#pragma unroll
    for (int ct = 0; ct < 2; ct++) {
      const unsigned short* tp = &Tl[B][ct * 16 + l16][quad * 8];
      bf16x8 b0 = *(const bf16x8*)tp;
      bf16x8 b1 = *(const bf16x8*)(tp + 32);
      f32x4 acc = {0.f, 0.f, 0.f, 0.f};
      acc = __builtin_amdgcn_mfma_f32_16x16x32_bf16(af0, b0, acc, 0, 0, 0);
      acc = __builtin_amdgcn_mfma_f32_16x16x32_bf16(af1, b1, acc, 0, 0, 0);
#pragma unroll
      for (int reg = 0; reg < 4; reg++)
        if (rr[reg] >= 0)
          out[((size_t)(bh * SS + rr[reg])) * SS + j0 + ct * 16 + l16] = acc[reg];
    }
  }
}

extern "C" void kernel_launch(void* const* d_in, const int* in_sizes, int n_in,
                              void* d_out, int out_size, void* d_ws, size_t ws_size,
                              hipStream_t stream) {
  const float* q = (const float*)d_in[0];
  const float* k = (const float*)d_in[1];
  const int* bseq = (const int*)d_in[2];
  const float* W1 = (const float*)d_in[3];
  const float* alpha = (const float*)d_in[4];
  float* out = (float*)d_out;
  char* ws = (char*)d_ws;
  unsigned short* W1mbf = (unsigned short*)(ws + WS_W1);
  int* ridx = (int*)(ws + WS_RIDX);
  int* gst = (int*)(ws + WS_GST);

  hipLaunchKernelGGL(k_prep, dim3(8 + NC * HH), dim3(256), 0, stream,
                     bseq, W1, alpha, ridx, gst, W1mbf);
  hipLaunchKernelGGL(k_fused, dim3(64 * (SS / CT)), dim3(256), 0, stream,
                     q, k, bseq, W1mbf, ridx, gst, out);
}

// Round 5
// 128.285 us; speedup vs baseline: 1.0811x; 1.0811x over previous
//
#include <hip/hip_runtime.h>
#include <stdint.h>

#define NB 4
#define NC 17
#define HH 8
#define SS 512
#define DD 64
#define CT 256   // columns per block tile (half the row)

typedef __attribute__((ext_vector_type(8))) short bf16x8;
typedef __attribute__((ext_vector_type(4))) float f32x4;

// ws layout (bytes):
//   W1mbf : [17][8][64][64] bf16 = 1,114,112
//   ridx  : [8][512] int (rows grouped by bucket bi)
//   gst   : [8][6] int group offsets
#define WS_W1   0
#define WS_RIDX 1114112
#define WS_GST  (WS_RIDX + 16384)

__device__ __forceinline__ unsigned short f2bf(float f) {
  unsigned int x; __builtin_memcpy(&x, &f, 4);
  return (unsigned short)((x + 0x7fff + ((x >> 16) & 1)) >> 16);
}
__device__ __forceinline__ bf16x8 cvt8(const float* p) {
  float4 a = *(const float4*)p;
  float4 b = *(const float4*)(p + 4);
  union { bf16x8 v; unsigned short u[8]; } t;
  t.u[0] = f2bf(a.x); t.u[1] = f2bf(a.y); t.u[2] = f2bf(a.z); t.u[3] = f2bf(a.w);
  t.u[4] = f2bf(b.x); t.u[5] = f2bf(b.y); t.u[6] = f2bf(b.z); t.u[7] = f2bf(b.w);
  return t.v;
}

// ---- K0: blocks 0..7: per-b counting sort of rows by bucket bi.
//          blocks 8..143: W1mbf[c][h][.] = sum_B W1[B][h][.]*softmax(alpha)[c,B,h]
__global__ __launch_bounds__(256) void k_prep(const int* __restrict__ bseq,
                                              const float* __restrict__ W1,
                                              const float* __restrict__ alpha,
                                              int* __restrict__ ridx,
                                              int* __restrict__ gst,
                                              unsigned short* __restrict__ W1mbf) {
  int tid = threadIdx.x;
  if (blockIdx.x < 8) {
    int b = blockIdx.x;
    __shared__ int cnt[5], base[6], cur[5];
    if (tid < 5) cnt[tid] = 0;
    __syncthreads();
    for (int j = tid; j < SS; j += blockDim.x) atomicAdd(&cnt[bseq[b * SS + j]], 1);
    __syncthreads();
    if (tid == 0) {
      base[0] = 0;
      for (int k = 0; k < 5; k++) base[k + 1] = base[k] + cnt[k];
      for (int k = 0; k < 6; k++) gst[b * 6 + k] = base[k];
    }
    __syncthreads();
    if (tid < 5) cur[tid] = base[tid];
    __syncthreads();
    for (int j = tid; j < SS; j += blockDim.x) {
      int p = atomicAdd(&cur[bseq[b * SS + j]], 1);
      ridx[b * SS + p] = j;
    }
  } else {
    int cb = blockIdx.x - 8;
    int c = cb >> 3, hh = cb & 7;
    __shared__ float sm[NB];
    if (tid == 0) {
      float a[NB], mx = -1e30f;
      for (int B = 0; B < NB; B++) { a[B] = alpha[(c * NB + B) * HH + hh]; mx = fmaxf(mx, a[B]); }
      float s = 0.f;
      for (int B = 0; B < NB; B++) { a[B] = __expf(a[B] - mx); s += a[B]; }
      for (int B = 0; B < NB; B++) sm[B] = a[B] / s;
    }
    __syncthreads();
    float s0 = sm[0], s1 = sm[1], s2 = sm[2], s3 = sm[3];
    for (int idx = tid; idx < DD * DD; idx += blockDim.x) {
      float v = W1[((0 * HH + hh) * DD * DD) + idx] * s0 +
                W1[((1 * HH + hh) * DD * DD) + idx] * s1 +
                W1[((2 * HH + hh) * DD * DD) + idx] * s2 +
                W1[((3 * HH + hh) * DD * DD) + idx] * s3;
      W1mbf[((size_t)(c * HH + hh)) * DD * DD + idx] = f2bf(v);
    }
  }
}

// ---- Fused: block = (bh, B-plane, 256-col half).
// Phase 1: T[col][m] for plane B over 256 local cols (class-uniform 16-tiles via
// local bj-grouping) into LDS. Phase 2: rows of bucket B (global ridx) x 256 cols.
__global__ __launch_bounds__(256) void k_fused(const float* __restrict__ query,
                                               const float* __restrict__ key,
                                               const int* __restrict__ bseq,
                                               const unsigned short* __restrict__ W1mbf,
                                               const int* __restrict__ ridx,
                                               const int* __restrict__ gst,
                                               float* __restrict__ out) {
  int bx = blockIdx.x;
  int bh = bx & 63, u = bx >> 6;        // same-bh blocks 64 apart -> same XCD
  int B = u % 5, half = u / 5;
  int b = bh >> 3, h = bh & 7;
  int j0 = half * CT;
  int tid = threadIdx.x, wave = tid >> 6, lane = tid & 63;
  int quad = lane >> 4, l16 = lane & 15;

  int gs = gst[b * 6 + B], ge = gst[b * 6 + B + 1];
  if (ge <= gs) return;  // no rows in this bucket: nothing to write

  __shared__ __align__(16) unsigned short Tl[CT][72];  // 36,864 B
  __shared__ int ord[CT], lgs[6], cnt[5], cur[5];
  __shared__ int p1list[24], n1s[5], n1b[5], n1tot;

  // ---- local column grouping by bj ----
  if (tid < 5) cnt[tid] = 0;
  __syncthreads();
  int mybj = bseq[b * SS + j0 + tid];
  atomicAdd(&cnt[mybj], 1);
  __syncthreads();
  if (tid == 0) {
    lgs[0] = 0;
    for (int a = 0; a < 5; a++) lgs[a + 1] = lgs[a] + cnt[a];
  }
  __syncthreads();
  if (tid < 5) cur[tid] = lgs[tid];
  __syncthreads();
  ord[atomicAdd(&cur[mybj], 1)] = tid;
  if (tid < 5) n1s[tid] = (lgs[tid + 1] - lgs[tid] + 15) >> 4;
  __syncthreads();
  if (tid == 0) {
    int a0 = 0;
    for (int a = 0; a < 5; a++) { n1b[a] = a0; a0 += n1s[a]; }
    n1tot = a0;
  }
  __syncthreads();
  if (tid < 5) {
    int a = tid;
    int ls = lgs[a], le = lgs[a + 1];
    int c = (B == 0 || a == 0) ? 0 : (B - 1) * NB + a;
    int w = n1b[a];
    for (int t0 = ls; t0 < le; t0 += 16)
      p1list[w++] = t0 | (le << 9) | (c << 18);
  }
  __syncthreads();

  // ---- phase 1: Tl[col][m] = sum_n key[col][n] * W_c[m][n] ----
  for (int idx = wave; idx < n1tot; idx += 4) {
    int e = p1list[idx];
    int t0 = e & 511, le = (e >> 9) & 511, c = e >> 18;
    const unsigned short* Wc = W1mbf + ((size_t)(c * HH + h) << 12);
    int p = t0 + l16; if (p > le - 1) p = le - 1;
    int cl = ord[p];
    const float* kp = &key[((size_t)(bh * SS + j0 + cl)) * DD + quad * 8];
    bf16x8 af0 = cvt8(kp);
    bf16x8 af1 = cvt8(kp + 32);
    int cr[4];
#pragma unroll
    for (int reg = 0; reg < 4; reg++) {
      int pr = t0 + quad * 4 + reg;
      cr[reg] = (pr < le) ? ord[pr] : -1;
    }
#pragma unroll
    for (int nt = 0; nt < 4; nt++) {
      const unsigned short* wp = &Wc[(nt * 16 + l16) * DD + quad * 8];
      bf16x8 b0 = *(const bf16x8*)wp;
      bf16x8 b1 = *(const bf16x8*)(wp + 32);
      f32x4 acc = {0.f, 0.f, 0.f, 0.f};
      acc = __builtin_amdgcn_mfma_f32_16x16x32_bf16(af0, b0, acc, 0, 0, 0);
      acc = __builtin_amdgcn_mfma_f32_16x16x32_bf16(af1, b1, acc, 0, 0, 0);
#pragma unroll
      for (int reg = 0; reg < 4; reg++)
        if (cr[reg] >= 0) Tl[cr[reg]][nt * 16 + l16] = f2bf(acc[reg]);
    }
  }
  __syncthreads();

  // ---- phase 2: out[r][j0+ct*16+l16] = q[r,:] dot Tl[col][:] ----
  for (int p0 = gs + wave * 16; p0 < ge; p0 += 64) {
    int p = p0 + l16; if (p > ge - 1) p = ge - 1;
    int r = ridx[b * SS + p];
    const float* qp = &query[((size_t)(bh * SS + r)) * DD + quad * 8];
    bf16x8 af0 = cvt8(qp);
    bf16x8 af1 = cvt8(qp + 32);
    int rr[4];
#pragma unroll
    for (int reg = 0; reg < 4; reg++) {
      int pr = p0 + quad * 4 + reg;
      rr[reg] = (pr < ge) ? ridx[b * SS + pr] : -1;
    }
#pragma unroll
    for (int ct = 0; ct < CT / 16; ct++) {
      const unsigned short* tp = &Tl[ct * 16 + l16][quad * 8];
      bf16x8 b0 = *(const bf16x8*)tp;
      bf16x8 b1 = *(const bf16x8*)(tp + 32);
      f32x4 acc = {0.f, 0.f, 0.f, 0.f};
      acc = __builtin_amdgcn_mfma_f32_16x16x32_bf16(af0, b0, acc, 0, 0, 0);
      acc = __builtin_amdgcn_mfma_f32_16x16x32_bf16(af1, b1, acc, 0, 0, 0);
#pragma unroll
      for (int reg = 0; reg < 4; reg++)
        if (rr[reg] >= 0)
          out[((size_t)(bh * SS + rr[reg])) * SS + j0 + ct * 16 + l16] = acc[reg];
    }
  }
}

extern "C" void kernel_launch(void* const* d_in, const int* in_sizes, int n_in,
                              void* d_out, int out_size, void* d_ws, size_t ws_size,
                              hipStream_t stream) {
  const float* q = (const float*)d_in[0];
  const float* k = (const float*)d_in[1];
  const int* bseq = (const int*)d_in[2];
  const float* W1 = (const float*)d_in[3];
  const float* alpha = (const float*)d_in[4];
  float* out = (float*)d_out;
  char* ws = (char*)d_ws;
  unsigned short* W1mbf = (unsigned short*)(ws + WS_W1);
  int* ridx = (int*)(ws + WS_RIDX);
  int* gst = (int*)(ws + WS_GST);

  hipLaunchKernelGGL(k_prep, dim3(8 + NC * HH), dim3(256), 0, stream,
                     bseq, W1, alpha, ridx, gst, W1mbf);
  hipLaunchKernelGGL(k_fused, dim3(64 * 5 * (SS / CT)), dim3(256), 0, stream,
                     q, k, bseq, W1mbf, ridx, gst, out);
}

// Round 6
// 119.841 us; speedup vs baseline: 1.1573x; 1.0705x over previous
//
#include <hip/hip_runtime.h>
#include <stdint.h>

#define NB 4
#define NC 17
#define HH 8
#define SS 512
#define DD 64
#define CT 64   // columns per block tile

typedef __attribute__((ext_vector_type(8))) short bf16x8;
typedef __attribute__((ext_vector_type(4))) float f32x4;

// ws layout (bytes):
//   W1mbf : [17][8][64][64] bf16 = 1,114,112
//   ridx  : [8][512] int (rows grouped by bucket bi)
//   gst   : [8][6] int group offsets
#define WS_W1   0
#define WS_RIDX 1114112
#define WS_GST  (WS_RIDX + 16384)

__device__ __forceinline__ unsigned short f2bf(float f) {
  unsigned int x; __builtin_memcpy(&x, &f, 4);
  return (unsigned short)((x + 0x7fff + ((x >> 16) & 1)) >> 16);
}
__device__ __forceinline__ bf16x8 cvt8(float4 a, float4 b) {
  union { bf16x8 v; unsigned short u[8]; } t;
  t.u[0] = f2bf(a.x); t.u[1] = f2bf(a.y); t.u[2] = f2bf(a.z); t.u[3] = f2bf(a.w);
  t.u[4] = f2bf(b.x); t.u[5] = f2bf(b.y); t.u[6] = f2bf(b.z); t.u[7] = f2bf(b.w);
  return t.v;
}

// ---- K0: blocks 0..7: per-b counting sort of rows by bucket bi.
//          blocks 8..143: W1mbf[c][h][.] = sum_B W1[B][h][.]*softmax(alpha)[c,B,h]
__global__ __launch_bounds__(256) void k_prep(const int* __restrict__ bseq,
                                              const float* __restrict__ W1,
                                              const float* __restrict__ alpha,
                                              int* __restrict__ ridx,
                                              int* __restrict__ gst,
                                              unsigned short* __restrict__ W1mbf) {
  int tid = threadIdx.x;
  if (blockIdx.x < 8) {
    int b = blockIdx.x;
    __shared__ int cnt[5], base[6], cur[5];
    if (tid < 5) cnt[tid] = 0;
    __syncthreads();
    for (int j = tid; j < SS; j += blockDim.x) atomicAdd(&cnt[bseq[b * SS + j]], 1);
    __syncthreads();
    if (tid == 0) {
      base[0] = 0;
      for (int k = 0; k < 5; k++) base[k + 1] = base[k] + cnt[k];
      for (int k = 0; k < 6; k++) gst[b * 6 + k] = base[k];
    }
    __syncthreads();
    if (tid < 5) cur[tid] = base[tid];
    __syncthreads();
    for (int j = tid; j < SS; j += blockDim.x) {
      int p = atomicAdd(&cur[bseq[b * SS + j]], 1);
      ridx[b * SS + p] = j;
    }
  } else {
    int cb = blockIdx.x - 8;
    int c = cb >> 3, hh = cb & 7;
    __shared__ float sm[NB];
    if (tid == 0) {
      float a[NB], mx = -1e30f;
      for (int B = 0; B < NB; B++) { a[B] = alpha[(c * NB + B) * HH + hh]; mx = fmaxf(mx, a[B]); }
      float s = 0.f;
      for (int B = 0; B < NB; B++) { a[B] = __expf(a[B] - mx); s += a[B]; }
      for (int B = 0; B < NB; B++) sm[B] = a[B] / s;
    }
    __syncthreads();
    float s0 = sm[0], s1 = sm[1], s2 = sm[2], s3 = sm[3];
    for (int idx = tid; idx < DD * DD; idx += blockDim.x) {
      float v = W1[((0 * HH + hh) * DD * DD) + idx] * s0 +
                W1[((1 * HH + hh) * DD * DD) + idx] * s1 +
                W1[((2 * HH + hh) * DD * DD) + idx] * s2 +
                W1[((3 * HH + hh) * DD * DD) + idx] * s3;
      W1mbf[((size_t)(c * HH + hh)) * DD * DD + idx] = f2bf(v);
    }
  }
}

// ---- Fused: block = (bh, 64-col tile). Phase 1 builds T[5][64][.] in LDS,
// phase 2 does the scores GEMM with 2-way row-tile ILP.
__global__ __launch_bounds__(512, 4) void k_fused(const float* __restrict__ query,
                                                  const float* __restrict__ key,
                                                  const int* __restrict__ bseq,
                                                  const unsigned short* __restrict__ W1mbf,
                                                  const int* __restrict__ ridx,
                                                  const int* __restrict__ gst,
                                                  float* __restrict__ out) {
  int bx = blockIdx.x;
  int bh = bx & 63, jt = bx >> 6;   // same-bh blocks 64 apart -> same XCD
  int b = bh >> 3, h = bh & 7;
  int j0 = jt * CT;
  int tid = threadIdx.x, wave = tid >> 6, lane = tid & 63;
  int quad = lane >> 4, l16 = lane & 15;

  __shared__ __align__(16) unsigned short Tl[5][CT][72];  // 46,080 B
  __shared__ int ord[CT], lgs[6], cnt[5], cur[5];
  __shared__ int p1list[40], p2list[40];
  __shared__ int n1s[5], n1b[5], n1tot, n2tot;

  // ---- local column grouping by bj ----
  if (tid < 5) cnt[tid] = 0;
  __syncthreads();
  int mybj = 0;
  if (tid < CT) { mybj = bseq[b * SS + j0 + tid]; atomicAdd(&cnt[mybj], 1); }
  __syncthreads();
  if (tid == 0) {
    lgs[0] = 0;
    for (int a = 0; a < 5; a++) lgs[a + 1] = lgs[a] + cnt[a];
  }
  __syncthreads();
  if (tid < 5) cur[tid] = lgs[tid];
  __syncthreads();
  if (tid < CT) ord[atomicAdd(&cur[mybj], 1)] = tid;
  if (tid < 5) n1s[tid] = ((lgs[tid + 1] - lgs[tid] + 15) >> 4) * ((tid == 0) ? 1 : 5);
  __syncthreads();
  if (tid == 0) {
    int a0 = 0;
    for (int a = 0; a < 5; a++) { n1b[a] = a0; a0 += n1s[a]; }
    n1tot = a0;
    int a1 = 0;
    for (int a = 0; a < 5; a++) a1 += (gst[b * 6 + a + 1] - gst[b * 6 + a] + 15) >> 4;
    n2tot = a1;
  }
  __syncthreads();
  if (tid < 5) {
    int a = tid;
    int ls = lgs[a], le = lgs[a + 1];
    int w = n1b[a];
    for (int t0 = ls; t0 < le; t0 += 16) {
      if (a == 0) {
        p1list[w++] = t0 | (le << 6) | (1 << 21);  // c=0, bcast all planes
      } else {
        for (int B = 0; B < 5; B++) {
          int c = (B == 0) ? 0 : (B - 1) * NB + a;
          p1list[w++] = t0 | (le << 6) | (c << 13) | (B << 18);
        }
      }
    }
    // phase-2 list: contiguous write region per bucket
    int w2 = 0;
    for (int aa = 0; aa < a; aa++) w2 += (gst[b * 6 + aa + 1] - gst[b * 6 + aa] + 15) >> 4;
    int gs = gst[b * 6 + a], ge = gst[b * 6 + a + 1];
    for (int p0 = gs; p0 < ge; p0 += 16)
      p2list[w2++] = p0 | (ge << 10) | (a << 20);
  }
  __syncthreads();

  // ---- phase 1: Tl[B][col][m] = sum_n key[col][n] * W_c(B,bj)[m][n] ----
  for (int idx = wave; idx < n1tot; idx += 8) {
    int e = p1list[idx];
    int t0 = e & 63, le = (e >> 6) & 127, c = (e >> 13) & 31, B = (e >> 18) & 7;
    int bc = (e >> 21) & 1;
    const unsigned short* Wc = W1mbf + ((size_t)(c * HH + h) << 12);
    int p = t0 + l16; if (p > le - 1) p = le - 1;
    int cl = ord[p];
    const float* kp = &key[((size_t)(bh * SS + j0 + cl)) * DD + quad * 8];
    float4 ka = *(const float4*)kp, kb = *(const float4*)(kp + 4);
    float4 kc = *(const float4*)(kp + 32), kd = *(const float4*)(kp + 36);
    bf16x8 af0 = cvt8(ka, kb);
    bf16x8 af1 = cvt8(kc, kd);
    int cr[4];
#pragma unroll
    for (int reg = 0; reg < 4; reg++) {
      int pr = t0 + quad * 4 + reg;
      cr[reg] = (pr < le) ? ord[pr] : -1;
    }
#pragma unroll
    for (int nt = 0; nt < 4; nt++) {
      const unsigned short* wp = &Wc[(nt * 16 + l16) * DD + quad * 8];
      bf16x8 b0 = *(const bf16x8*)wp;
      bf16x8 b1 = *(const bf16x8*)(wp + 32);
      f32x4 acc = {0.f, 0.f, 0.f, 0.f};
      acc = __builtin_amdgcn_mfma_f32_16x16x32_bf16(af0, b0, acc, 0, 0, 0);
      acc = __builtin_amdgcn_mfma_f32_16x16x32_bf16(af1, b1, acc, 0, 0, 0);
#pragma unroll
      for (int reg = 0; reg < 4; reg++) {
        if (cr[reg] >= 0) {
          unsigned short v = f2bf(acc[reg]);
          if (bc) {
#pragma unroll
            for (int Bw = 0; Bw < 5; Bw++) Tl[Bw][cr[reg]][nt * 16 + l16] = v;
          } else {
            Tl[B][cr[reg]][nt * 16 + l16] = v;
          }
        }
      }
    }
  }
  __syncthreads();

  // ---- phase 2: out[r][j0..j0+63] = q[r,:] dot Tl[bi(r)][col][:], 2-way ILP ----
  for (int i0 = wave * 2; i0 < n2tot; i0 += 16) {
    int e0 = p2list[i0];
    bool has1 = (i0 + 1) < n2tot;
    int e1 = has1 ? p2list[i0 + 1] : e0;

    int p0a = e0 & 1023, gea = (e0 >> 10) & 1023, Ba = e0 >> 20;
    int p0b = e1 & 1023, geb = (e1 >> 10) & 1023, Bb = e1 >> 20;

    int pa = p0a + l16; if (pa > gea - 1) pa = gea - 1;
    int pb = p0b + l16; if (pb > geb - 1) pb = geb - 1;
    int ra = ridx[b * SS + pa];
    int rb = ridx[b * SS + pb];
    const float* qa = &query[((size_t)(bh * SS + ra)) * DD + quad * 8];
    const float* qb = &query[((size_t)(bh * SS + rb)) * DD + quad * 8];
    // issue all 8 global loads before converting
    float4 a0 = *(const float4*)qa, a1 = *(const float4*)(qa + 4);
    float4 a2 = *(const float4*)(qa + 32), a3 = *(const float4*)(qa + 36);
    float4 b0_ = *(const float4*)qb, b1_ = *(const float4*)(qb + 4);
    float4 b2_ = *(const float4*)(qb + 32), b3_ = *(const float4*)(qb + 36);
    bf16x8 afa0 = cvt8(a0, a1), afa1 = cvt8(a2, a3);
    bf16x8 afb0 = cvt8(b0_, b1_), afb1 = cvt8(b2_, b3_);

    int rra[4], rrb[4];
#pragma unroll
    for (int reg = 0; reg < 4; reg++) {
      int pra = p0a + quad * 4 + reg;
      rra[reg] = (pra < gea) ? ridx[b * SS + pra] : -1;
      int prb = p0b + quad * 4 + reg;
      rrb[reg] = (has1 && prb < geb) ? ridx[b * SS + prb] : -1;
    }
#pragma unroll
    for (int ct = 0; ct < CT / 16; ct++) {
      const unsigned short* tpa = &Tl[Ba][ct * 16 + l16][quad * 8];
      const unsigned short* tpb = &Tl[Bb][ct * 16 + l16][quad * 8];
      bf16x8 ba0 = *(const bf16x8*)tpa;
      bf16x8 ba1 = *(const bf16x8*)(tpa + 32);
      bf16x8 bb0 = *(const bf16x8*)tpb;
      bf16x8 bb1 = *(const bf16x8*)(tpb + 32);
      f32x4 acca = {0.f, 0.f, 0.f, 0.f}, accb = {0.f, 0.f, 0.f, 0.f};
      acca = __builtin_amdgcn_mfma_f32_16x16x32_bf16(afa0, ba0, acca, 0, 0, 0);
      accb = __builtin_amdgcn_mfma_f32_16x16x32_bf16(afb0, bb0, accb, 0, 0, 0);
      acca = __builtin_amdgcn_mfma_f32_16x16x32_bf16(afa1, ba1, acca, 0, 0, 0);
      accb = __builtin_amdgcn_mfma_f32_16x16x32_bf16(afb1, bb1, accb, 0, 0, 0);
#pragma unroll
      for (int reg = 0; reg < 4; reg++) {
        if (rra[reg] >= 0)
          out[((size_t)(bh * SS + rra[reg])) * SS + j0 + ct * 16 + l16] = acca[reg];
        if (rrb[reg] >= 0)
          out[((size_t)(bh * SS + rrb[reg])) * SS + j0 + ct * 16 + l16] = accb[reg];
      }
    }
  }
}

extern "C" void kernel_launch(void* const* d_in, const int* in_sizes, int n_in,
                              void* d_out, int out_size, void* d_ws, size_t ws_size,
                              hipStream_t stream) {
  const float* q = (const float*)d_in[0];
  const float* k = (const float*)d_in[1];
  const int* bseq = (const int*)d_in[2];
  const float* W1 = (const float*)d_in[3];
  const float* alpha = (const float*)d_in[4];
  float* out = (float*)d_out;
  char* ws = (char*)d_ws;
  unsigned short* W1mbf = (unsigned short*)(ws + WS_W1);
  int* ridx = (int*)(ws + WS_RIDX);
  int* gst = (int*)(ws + WS_GST);

  hipLaunchKernelGGL(k_prep, dim3(8 + NC * HH), dim3(256), 0, stream,
                     bseq, W1, alpha, ridx, gst, W1mbf);
  hipLaunchKernelGGL(k_fused, dim3(64 * (SS / CT)), dim3(512), 0, stream,
                     q, k, bseq, W1mbf, ridx, gst, out);
}